// Round 6
// baseline (1915.834 us; speedup 1.0000x reference)
//
#include <hip/hip_runtime.h>

typedef unsigned short u16;
typedef unsigned int u32;
typedef long long i64;

#define NAT 200000
#define NBL 50000
#define NGR 64
#define HID 128
#define RAD 64
#define EDG 256
#define NLY 3
#define NED 450000

typedef __bf16 bf16x8 __attribute__((ext_vector_type(8)));
typedef float f32x4 __attribute__((ext_vector_type(4)));

__device__ __forceinline__ float b2f(u16 u) {
    u32 x = ((u32)u) << 16; float f; __builtin_memcpy(&f, &x, 4); return f;
}
__device__ __forceinline__ u16 f2b(float f) {
    u32 x; __builtin_memcpy(&x, &f, 4);
    u32 r = x + 0x7fffu + ((x >> 16) & 1u);
    return (u16)(r >> 16);
}
__device__ __forceinline__ float silu_f(float v) { return v / (1.0f + __expf(-v)); }

__device__ __forceinline__ float ld_in(const void* p, size_t i, int isf) {
    return isf ? ((const float*)p)[i] : b2f(((const u16*)p)[i]);
}
__device__ __forceinline__ int ld_idx(const void* p, size_t i, int i64f) {
    return i64f ? (int)((const i64*)p)[i] : ((const int*)p)[i];
}

// ---- detect float input dtype from H (verified working R2-R5) ----
__global__ void detect_k(const void* __restrict__ H, int* __restrict__ flag) {
    const u16* p = (const u16*)H;
    int c = 0;
    for (int i = threadIdx.x; i < 4096; i += 256) {
        u16 u = p[2 * i];
        int e = (u >> 7) & 0xFF;
        if ((e >= 0x9E) || (e <= 0x5E && (u & 0x7FFFu) != 0)) c++;
    }
    __shared__ int red[256];
    red[threadIdx.x] = c;
    __syncthreads();
    for (int o = 128; o; o >>= 1) { if (threadIdx.x < o) red[threadIdx.x] += red[threadIdx.x + o]; __syncthreads(); }
    if (threadIdx.x == 0) flag[0] = (red[0] > 256) ? 1 : 0;
}

// ---- detect integer width from block_id (verified: int32 on this harness) ----
__global__ void detecti_k(const void* __restrict__ bid, int* __restrict__ iflag) {
    const int* p = (const int*)bid;
    int c = 0;
    for (int i = threadIdx.x; i < 1024; i += 256) {
        if (p[100001 + 2 * i] == 0) c++;
    }
    __shared__ int red[256];
    red[threadIdx.x] = c;
    __syncthreads();
    for (int o = 128; o; o >>= 1) { if (threadIdx.x < o) red[threadIdx.x] += red[threadIdx.x + o]; __syncthreads(); }
    if (threadIdx.x == 0) iflag[0] = (red[0] > 512) ? 1 : 0;
}

// ---- lower_bound ranges over a sorted id array ----
__global__ void find_starts_k(const void* __restrict__ ids, int n, int nbins,
                              const int* __restrict__ iflag, int* __restrict__ out) {
    int i64f = iflag[0];
    int b = blockIdx.x * blockDim.x + threadIdx.x;
    if (b > nbins) return;
    int lo = 0, hi = n;
    while (lo < hi) { int mid = (lo + hi) >> 1; if (ld_idx(ids, mid, i64f) < b) lo = mid + 1; else hi = mid; }
    out[b] = lo;
}

// ---- scatter-mean pooling: atoms -> blocks; out0 (f32) written directly ----
__global__ void pool_k(const void* __restrict__ H, const void* __restrict__ Z,
                       const int* __restrict__ start, const int* __restrict__ flag,
                       float* __restrict__ out0, u16* __restrict__ hbf,
                       float* __restrict__ Zb) {
    int b = blockIdx.x, c = threadIdx.x;
    int isf = flag[0];
    int s = start[b], e = start[b + 1];
    float inv = 1.0f / (float)max(e - s, 1);
    float sum = 0.f;
    for (int a = s; a < e; a++) sum += ld_in(H, (size_t)a * HID + c, isf);
    float m = sum * inv;
    out0[(size_t)b * HID + c] = m;
    hbf[(size_t)b * HID + c] = f2b(m);
    if (c < 3) {
        float zs = 0.f;
        for (int a = s; a < e; a++) zs += ld_in(Z, (size_t)a * 3 + c, isf);
        Zb[(size_t)b * 3 + c] = zs * inv;
    }
}

// ---- W2T[l][c][a] = (W_rbf @ We[l])^T : [256][64] per layer ----
__global__ void w2t_k(const void* __restrict__ W_rbf, const void* __restrict__ We,
                      const int* __restrict__ flag, u16* __restrict__ W2T) {
    int isf = flag[0];
    int l = blockIdx.y;
    int gid = blockIdx.x * 256 + threadIdx.x;
    int c = gid >> 6, a = gid & 63;
    float s = 0.f;
    for (int j = 0; j < EDG; j++)
        s += ld_in(W_rbf, a * EDG + j, isf) * ld_in(We, (size_t)l * EDG * EDG + j * EDG + c, isf);
    W2T[l * EDG * RAD + c * RAD + a] = f2b(s);
}

// ---- transpose raw [R][C] (element base) -> bf16 [C][R] ----
__global__ void xpose_k(const void* __restrict__ in, size_t elemBase, u16* __restrict__ out,
                        int R, int C, const int* __restrict__ flag) {
    int isf = flag[0];
    int gid = blockIdx.x * 256 + threadIdx.x;
    if (gid >= R * C) return;
    int r = gid / C, c = gid - r * C;
    out[c * R + r] = f2b(ld_in(in, elemBase + gid, isf));
}

// ---- per-edge distance ----
__global__ void dist_k(const void* __restrict__ edges, const float* __restrict__ Zb,
                       const int* __restrict__ iflag, float* __restrict__ dist) {
    int i64f = iflag[0];
    int e = blockIdx.x * 256 + threadIdx.x;
    if (e >= NED) return;
    int s = ld_idx(edges, e, i64f), d = ld_idx(edges, (size_t)NED + e, i64f);
    float dx = Zb[s * 3 + 0] - Zb[d * 3 + 0];
    float dy = Zb[s * 3 + 1] - Zb[d * 3 + 1];
    float dz = Zb[s * 3 + 2] - Zb[d * 3 + 2];
    dist[e] = sqrtf(dx * dx + dy * dy + dz * dz + 1e-12f);
}

// ---- generic MFMA GEMM, tile 64(M) x (16*NFRAG)(N), K-chunks of 64 ----
enum { EP_B16 = 0, EP_F32 = 1, EP_MSG = 2, EP_ACC = 3 };

template<int MODE, int K, int NFRAG>
__global__ __launch_bounds__(256) void gemm_k(
    const u16* __restrict__ A, const float* __restrict__ Af, int M, int ldA,
    const float* __restrict__ dist,
    const u16* __restrict__ BT, int ldB,
    u16* __restrict__ outB, float* __restrict__ outF, int ldOut,
    const void* __restrict__ edg, const int* __restrict__ iflag,
    const u16* __restrict__ P1, const u16* __restrict__ P2, int ldP,
    float* __restrict__ agg,
    float* __restrict__ hacc)
{
    __shared__ __attribute__((aligned(16))) u16 sA[64 * 72];
    __shared__ __attribute__((aligned(16))) u16 sB[128 * 72];
    __shared__ int sSrc[64];
    __shared__ int sDst[64];
    __shared__ float sDist[64];
    const int tid = threadIdx.x;
    const int w = tid >> 6, lane = tid & 63, quad = lane >> 4, m16 = lane & 15;
    const int rowBase = blockIdx.x * 64;
    const int nt = blockIdx.y;
    f32x4 acc[NFRAG];
#pragma unroll
    for (int f = 0; f < NFRAG; f++) acc[f] = (f32x4){0.f, 0.f, 0.f, 0.f};

    if (MODE == EP_MSG) {
        if (tid < 64) {
            int i64f = iflag[0];
            int e = min(rowBase + tid, M - 1);
            sSrc[tid] = ld_idx(edg, e, i64f);
            sDst[tid] = ld_idx(edg, (size_t)NED + e, i64f);
            sDist[tid] = dist[e];
        }
        __syncthreads();
    }

    for (int kc = 0; kc < K; kc += 64) {
        if (MODE == EP_MSG) {
            int row = tid >> 2, kb = (tid & 3) * 16;
            float dd = sDist[row];
#pragma unroll
            for (int j = 0; j < 16; j++) {
                int k = kb + j;
                float u = dd - (float)k * (6.0f / 63.0f);
                sA[row * 72 + k] = f2b(__expf(-10.0f * u * u));
            }
        } else if (MODE == EP_ACC) {
#pragma unroll
            for (int p = tid; p < 512; p += 256) {
                int row = p >> 3, sub = p & 7;
                int gr = min(rowBase + row, M - 1);
                const float* sp = Af + (size_t)gr * ldA + kc + sub * 8;
                float4 v0 = *(const float4*)(const void*)sp;
                float4 v1 = *(const float4*)(const void*)(sp + 4);
                uint4 pk;
                pk.x = (u32)f2b(v0.x) | ((u32)f2b(v0.y) << 16);
                pk.y = (u32)f2b(v0.z) | ((u32)f2b(v0.w) << 16);
                pk.z = (u32)f2b(v1.x) | ((u32)f2b(v1.y) << 16);
                pk.w = (u32)f2b(v1.z) | ((u32)f2b(v1.w) << 16);
                *(uint4*)(void*)(&sA[row * 72 + sub * 8]) = pk;
            }
        } else {
#pragma unroll
            for (int p = tid; p < 512; p += 256) {
                int row = p >> 3, sub = p & 7;
                int gr = min(rowBase + row, M - 1);
                uint4 v = *(const uint4*)(const void*)(A + (size_t)gr * ldA + kc + sub * 8);
                *(uint4*)(void*)(&sA[row * 72 + sub * 8]) = v;
            }
        }
#pragma unroll
        for (int p = tid; p < NFRAG * 128; p += 256) {
            int row = p >> 3, sub = p & 7;
            uint4 v = *(const uint4*)(const void*)(BT + (size_t)(nt * 16 * NFRAG + row) * ldB + kc + sub * 8);
            *(uint4*)(void*)(&sB[row * 72 + sub * 8]) = v;
        }
        __syncthreads();
#pragma unroll
        for (int ks = 0; ks < 2; ks++) {
            bf16x8 af = *(const bf16x8*)(const void*)(&sA[(w * 16 + m16) * 72 + ks * 32 + quad * 8]);
#pragma unroll
            for (int f = 0; f < NFRAG; f++) {
                bf16x8 bfr = *(const bf16x8*)(const void*)(&sB[(f * 16 + m16) * 72 + ks * 32 + quad * 8]);
                acc[f] = __builtin_amdgcn_mfma_f32_16x16x32_bf16(af, bfr, acc[f], 0, 0, 0);
            }
        }
        __syncthreads();
    }

    // C/D layout: col = 16*f + (lane&15), row = 16*w + quad*4 + reg
#pragma unroll
    for (int f = 0; f < NFRAG; f++) {
        int col = nt * 16 * NFRAG + f * 16 + m16;
#pragma unroll
        for (int rg = 0; rg < 4; rg++) {
            int rl = w * 16 + quad * 4 + rg;
            int r = rowBase + rl;
            if (r < M) {
                float v = acc[f][rg];
                if (MODE == EP_B16) {
                    outB[(size_t)r * ldOut + col] = f2b(v);
                } else if (MODE == EP_F32) {
                    outF[(size_t)r * ldOut + col] = v;
                } else if (MODE == EP_MSG) {
                    int s = sSrc[rl], dd = sDst[rl];
                    v += b2f(P1[(size_t)s * ldP + col]) + b2f(P2[(size_t)dd * ldP + col]);
                    v = silu_f(v);
                    atomicAdd(&agg[(size_t)dd * ldP + col], v);
                } else {
                    hacc[(size_t)r * HID + col] += v;
                }
            }
        }
    }
}

// ---- finalize layer: hbf += silu(hacc) ----
__global__ void finalize_k(const float* __restrict__ hacc, u16* __restrict__ hbf) {
    int gid = blockIdx.x * 256 + threadIdx.x;
    float nh = b2f(hbf[gid]) + silu_f(hacc[gid]);
    hbf[gid] = f2b(nh);
}

// ---- block_repr row l2norm -> out1 (f32) ----
__global__ void normb_k(const float* __restrict__ brepr, float* __restrict__ out1) {
    int t = blockIdx.x * 256 + threadIdx.x;
    int b = t >> 6, lane = t & 63;
    float2 x = *(const float2*)(const void*)&brepr[(size_t)b * HID + lane * 2];
    float ss = x.x * x.x + x.y * x.y;
#pragma unroll
    for (int off = 32; off; off >>= 1) ss += __shfl_xor(ss, off);
    float inv = 1.0f / fmaxf(sqrtf(ss), 1e-12f);
    float2 o = make_float2(x.x * inv, x.y * inv);
    *(float2*)(void*)&out1[(size_t)b * HID + lane * 2] = o;
}

// ---- graph readout: CSR sum over sorted batch_id + l2norm -> out2 (f32) ----
__global__ void gsum_k(const float* __restrict__ out1, const int* __restrict__ gstart,
                       float* __restrict__ out2) {
    int g = blockIdx.x, c = threadIdx.x;
    int s = gstart[g], e = gstart[g + 1];
    float sum = 0.f;
    for (int r = s; r < e; r++) sum += out1[(size_t)r * HID + c];
    __shared__ float red[HID];
    red[c] = sum * sum;
    __syncthreads();
    for (int o = 64; o; o >>= 1) { if (c < o) red[c] += red[c + o]; __syncthreads(); }
    float inv = 1.0f / fmaxf(sqrtf(red[0]), 1e-12f);
    out2[(size_t)g * HID + c] = sum * inv;
}

extern "C" void kernel_launch(void* const* d_in, const int* in_sizes, int n_in,
                              void* d_out, int out_size, void* d_ws, size_t ws_size,
                              hipStream_t stream) {
    int iH = 0, iZ = 1, iWrbf = 2, iWm1 = 3, iWm2 = 4, iWe = 5, iWupd = 6, iWout = 7,
        iBid = 8, iGid = 9, iEdg = 10;
    {
        int h = -1, z = -1, we = -1, ed = -1, bi = -1, gi = -1;
        int s16[2] = {-1, -1}; int n16 = 0;
        int s98[3] = {-1, -1, -1}; int n98 = 0;
        for (int i = 0; i < n_in; i++) {
            int s = in_sizes[i];
            if (s == 25600000) h = i;
            else if (s == 600000) z = i;
            else if (s == 196608) we = i;
            else if (s == 900000) ed = i;
            else if (s == 200000) bi = i;
            else if (s == 50000) gi = i;
            else if (s == 16384 && n16 < 2) s16[n16++] = i;
            else if (s == 98304 && n98 < 3) s98[n98++] = i;
        }
        if (h >= 0 && z >= 0 && we >= 0 && ed >= 0 && bi >= 0 && gi >= 0 && n16 == 2 && n98 == 3) {
            iH = h; iZ = z; iWe = we; iEdg = ed; iBid = bi; iGid = gi;
            iWm1 = s98[0]; iWm2 = s98[1]; iWupd = s98[2];
            bool alpha = (s16[0] == 1 && s16[1] == 2);
            iWout = alpha ? s16[0] : s16[1];
            iWrbf = alpha ? s16[1] : s16[0];
        }
    }
    const void* H     = d_in[iH];
    const void* Z     = d_in[iZ];
    const void* W_rbf = d_in[iWrbf];
    const void* Wm1   = d_in[iWm1];
    const void* Wm2   = d_in[iWm2];
    const void* We    = d_in[iWe];
    const void* Wupd  = d_in[iWupd];
    const void* W_out = d_in[iWout];
    const void* block_id = d_in[iBid];
    const void* batch_id = d_in[iGid];
    const void* edges    = d_in[iEdg];

    const size_t MB = 1024 * 1024;
    int S = (ws_size >= 146 * MB) ? 1 : (ws_size >= 95 * MB) ? 2 : 4;
    const int NC = 256 / S;

    char* ws = (char*)d_ws;
    size_t off = 0;
    auto alloc = [&](size_t bytes) -> void* {
        void* p = ws + off;
        off += (bytes + 255) & ~(size_t)255;
        return p;
    };
    int*   flag   = (int*)alloc(256);
    int*   iflag  = (int*)alloc(256);
    int*   start  = (int*)alloc((NBL + 1) * sizeof(int));
    int*   gstart = (int*)alloc((NGR + 1) * sizeof(int));
    u16*   hbf    = (u16*)alloc((size_t)NBL * HID * 2);
    float* Zb     = (float*)alloc((size_t)NBL * 3 * 4);
    float* dist   = (float*)alloc((size_t)NED * 4);
    u16*   W2T    = (u16*)alloc((size_t)NLY * EDG * RAD * 2);
    u16*   Wm1T   = (u16*)alloc((size_t)NLY * EDG * HID * 2);
    u16*   Wm2T   = (u16*)alloc((size_t)NLY * EDG * HID * 2);
    u16*   WupdT  = (u16*)alloc((size_t)NLY * HID * EDG * 2);
    u16*   WoutT  = (u16*)alloc((size_t)HID * HID * 2);
    u16*   P1c    = (u16*)alloc((size_t)NBL * NC * 2);
    u16*   P2c    = (u16*)alloc((size_t)NBL * NC * 2);
    float* aggc   = (float*)alloc((size_t)NBL * NC * 4);
    float* hacc   = (float*)alloc((size_t)NBL * HID * 4);
    float* brepr  = hacc;   // overlay: hacc dead after last finalize

    // OUTPUTS ARE FLOAT32 (f32-decode theory: bf16 label is hard-coded in harness)
    float* out0 = (float*)d_out;
    float* out1 = out0 + (size_t)NBL * HID;
    float* out2 = out1 + (size_t)NBL * HID;

    const int TNB = (NBL + 63) / 64;
    const int TNE = (NED + 63) / 64;

    detect_k<<<1, 256, 0, stream>>>(H, flag);
    detecti_k<<<1, 256, 0, stream>>>(block_id, iflag);
    find_starts_k<<<(NBL + 256) / 256, 256, 0, stream>>>(block_id, NAT, NBL, iflag, start);
    find_starts_k<<<1, 256, 0, stream>>>(batch_id, NBL, NGR, iflag, gstart);
    pool_k<<<NBL, HID, 0, stream>>>(H, Z, start, flag, out0, hbf, Zb);
    w2t_k<<<dim3(64, NLY), 256, 0, stream>>>(W_rbf, We, flag, W2T);
    for (int l = 0; l < NLY; l++) {
        xpose_k<<<128, 256, 0, stream>>>(Wm1, (size_t)l * HID * EDG, Wm1T + (size_t)l * EDG * HID, HID, EDG, flag);
        xpose_k<<<128, 256, 0, stream>>>(Wm2, (size_t)l * HID * EDG, Wm2T + (size_t)l * EDG * HID, HID, EDG, flag);
        xpose_k<<<128, 256, 0, stream>>>(Wupd, (size_t)l * EDG * HID, WupdT + (size_t)l * HID * EDG, EDG, HID, flag);
    }
    xpose_k<<<64, 256, 0, stream>>>(W_out, 0, WoutT, HID, HID, flag);
    dist_k<<<(NED + 255) / 256, 256, 0, stream>>>(edges, Zb, iflag, dist);

    for (int l = 0; l < NLY; l++) {
        hipMemsetAsync(hacc, 0, (size_t)NBL * HID * 4, stream);
        for (int c = 0; c < S; c++) {
            const int c0 = c * NC;
            const u16* bWm1 = Wm1T + (size_t)l * EDG * HID + (size_t)c0 * HID;
            const u16* bWm2 = Wm2T + (size_t)l * EDG * HID + (size_t)c0 * HID;
            const u16* bW2  = W2T  + (size_t)l * EDG * RAD + (size_t)c0 * RAD;
            const u16* bWu  = WupdT + (size_t)l * HID * EDG + c0;
            hipMemsetAsync(aggc, 0, (size_t)NBL * NC * 4, stream);
            if (S == 1) {
                gemm_k<EP_B16, 128, 8><<<dim3(TNB, 2), 256, 0, stream>>>(
                    hbf, nullptr, NBL, HID, nullptr, bWm1, HID, P1c, nullptr, NC,
                    nullptr, nullptr, nullptr, nullptr, 0, nullptr, nullptr);
                gemm_k<EP_B16, 128, 8><<<dim3(TNB, 2), 256, 0, stream>>>(
                    hbf, nullptr, NBL, HID, nullptr, bWm2, HID, P2c, nullptr, NC,
                    nullptr, nullptr, nullptr, nullptr, 0, nullptr, nullptr);
                gemm_k<EP_MSG, 64, 8><<<dim3(TNE, 2), 256, 0, stream>>>(
                    nullptr, nullptr, NED, 0, dist, bW2, RAD, nullptr, nullptr, 0,
                    edges, iflag, P1c, P2c, NC, aggc, nullptr);
                gemm_k<EP_ACC, 256, 8><<<dim3(TNB, 1), 256, 0, stream>>>(
                    nullptr, aggc, NBL, NC, nullptr, bWu, EDG, nullptr, nullptr, 0,
                    nullptr, nullptr, nullptr, nullptr, 0, nullptr, hacc);
            } else if (S == 2) {
                gemm_k<EP_B16, 128, 8><<<dim3(TNB, 1), 256, 0, stream>>>(
                    hbf, nullptr, NBL, HID, nullptr, bWm1, HID, P1c, nullptr, NC,
                    nullptr, nullptr, nullptr, nullptr, 0, nullptr, nullptr);
                gemm_k<EP_B16, 128, 8><<<dim3(TNB, 1), 256, 0, stream>>>(
                    hbf, nullptr, NBL, HID, nullptr, bWm2, HID, P2c, nullptr, NC,
                    nullptr, nullptr, nullptr, nullptr, 0, nullptr, nullptr);
                gemm_k<EP_MSG, 64, 8><<<dim3(TNE, 1), 256, 0, stream>>>(
                    nullptr, nullptr, NED, 0, dist, bW2, RAD, nullptr, nullptr, 0,
                    edges, iflag, P1c, P2c, NC, aggc, nullptr);
                gemm_k<EP_ACC, 128, 8><<<dim3(TNB, 1), 256, 0, stream>>>(
                    nullptr, aggc, NBL, NC, nullptr, bWu, EDG, nullptr, nullptr, 0,
                    nullptr, nullptr, nullptr, nullptr, 0, nullptr, hacc);
            } else {
                gemm_k<EP_B16, 128, 4><<<dim3(TNB, 1), 256, 0, stream>>>(
                    hbf, nullptr, NBL, HID, nullptr, bWm1, HID, P1c, nullptr, NC,
                    nullptr, nullptr, nullptr, nullptr, 0, nullptr, nullptr);
                gemm_k<EP_B16, 128, 4><<<dim3(TNB, 1), 256, 0, stream>>>(
                    hbf, nullptr, NBL, HID, nullptr, bWm2, HID, P2c, nullptr, NC,
                    nullptr, nullptr, nullptr, nullptr, 0, nullptr, nullptr);
                gemm_k<EP_MSG, 64, 4><<<dim3(TNE, 1), 256, 0, stream>>>(
                    nullptr, nullptr, NED, 0, dist, bW2, RAD, nullptr, nullptr, 0,
                    edges, iflag, P1c, P2c, NC, aggc, nullptr);
                gemm_k<EP_ACC, 64, 8><<<dim3(TNB, 1), 256, 0, stream>>>(
                    nullptr, aggc, NBL, NC, nullptr, bWu, EDG, nullptr, nullptr, 0,
                    nullptr, nullptr, nullptr, nullptr, 0, nullptr, hacc);
            }
        }
        finalize_k<<<(size_t)NBL * HID / 256, 256, 0, stream>>>(hacc, hbf);
    }

    // block_repr (unnormalized) = h @ W_out -> f32 brepr
    gemm_k<EP_F32, 128, 8><<<dim3(TNB, 1), 256, 0, stream>>>(
        hbf, nullptr, NBL, HID, nullptr, WoutT, HID, nullptr, brepr, HID,
        nullptr, nullptr, nullptr, nullptr, 0, nullptr, nullptr);
    normb_k<<<(size_t)NBL * 64 / 256, 256, 0, stream>>>(brepr, out1);
    gsum_k<<<NGR, HID, 0, stream>>>(out1, gstart, out2);
}

// Round 7
// 1032.308 us; speedup vs baseline: 1.8559x; 1.8559x over previous
//
#include <hip/hip_runtime.h>

typedef unsigned short u16;
typedef unsigned int u32;
typedef long long i64;

#define NAT 200000
#define NBL 50000
#define NGR 64
#define HID 128
#define RAD 64
#define EDG 256
#define NLY 3
#define NED 450000
#define TSAMP 1024   // table samples over d in [0,8); 1025 rows stored

typedef __bf16 bf16x8 __attribute__((ext_vector_type(8)));
typedef float f32x4 __attribute__((ext_vector_type(4)));

__device__ __forceinline__ float b2f(u16 u) {
    u32 x = ((u32)u) << 16; float f; __builtin_memcpy(&f, &x, 4); return f;
}
__device__ __forceinline__ u16 f2b(float f) {
    u32 x; __builtin_memcpy(&x, &f, 4);
    u32 r = x + 0x7fffu + ((x >> 16) & 1u);
    return (u16)(r >> 16);
}
__device__ __forceinline__ float silu_f(float v) { return v / (1.0f + __expf(-v)); }

__device__ __forceinline__ float ld_in(const void* p, size_t i, int isf) {
    return isf ? ((const float*)p)[i] : b2f(((const u16*)p)[i]);
}
__device__ __forceinline__ int ld_idx(const void* p, size_t i, int i64f) {
    return i64f ? (int)((const i64*)p)[i] : ((const int*)p)[i];
}

// ---- detect float input dtype from H ----
__global__ void detect_k(const void* __restrict__ H, int* __restrict__ flag) {
    const u16* p = (const u16*)H;
    int c = 0;
    for (int i = threadIdx.x; i < 4096; i += 256) {
        u16 u = p[2 * i];
        int e = (u >> 7) & 0xFF;
        if ((e >= 0x9E) || (e <= 0x5E && (u & 0x7FFFu) != 0)) c++;
    }
    __shared__ int red[256];
    red[threadIdx.x] = c;
    __syncthreads();
    for (int o = 128; o; o >>= 1) { if (threadIdx.x < o) red[threadIdx.x] += red[threadIdx.x + o]; __syncthreads(); }
    if (threadIdx.x == 0) flag[0] = (red[0] > 256) ? 1 : 0;
}

// ---- detect integer width from block_id ----
__global__ void detecti_k(const void* __restrict__ bid, int* __restrict__ iflag) {
    const int* p = (const int*)bid;
    int c = 0;
    for (int i = threadIdx.x; i < 1024; i += 256) {
        if (p[100001 + 2 * i] == 0) c++;
    }
    __shared__ int red[256];
    red[threadIdx.x] = c;
    __syncthreads();
    for (int o = 128; o; o >>= 1) { if (threadIdx.x < o) red[threadIdx.x] += red[threadIdx.x + o]; __syncthreads(); }
    if (threadIdx.x == 0) iflag[0] = (red[0] > 512) ? 1 : 0;
}

// ---- lower_bound ranges over a sorted id array ----
__global__ void find_starts_k(const void* __restrict__ ids, int n, int nbins,
                              const int* __restrict__ iflag, int* __restrict__ out) {
    int i64f = iflag[0];
    int b = blockIdx.x * blockDim.x + threadIdx.x;
    if (b > nbins) return;
    int lo = 0, hi = n;
    while (lo < hi) { int mid = (lo + hi) >> 1; if (ld_idx(ids, mid, i64f) < b) lo = mid + 1; else hi = mid; }
    out[b] = lo;
}

// ---- scatter-mean pooling: out0 (f32) + bf16 state + Zb ----
__global__ void pool_k(const void* __restrict__ H, const void* __restrict__ Z,
                       const int* __restrict__ start, const int* __restrict__ flag,
                       float* __restrict__ out0, u16* __restrict__ hbf,
                       float* __restrict__ Zb) {
    int b = blockIdx.x, c = threadIdx.x;
    int isf = flag[0];
    int s = start[b], e = start[b + 1];
    float inv = 1.0f / (float)max(e - s, 1);
    float sum = 0.f;
    for (int a = s; a < e; a++) sum += ld_in(H, (size_t)a * HID + c, isf);
    float m = sum * inv;
    out0[(size_t)b * HID + c] = m;
    hbf[(size_t)b * HID + c] = f2b(m);
    if (c < 3) {
        float zs = 0.f;
        for (int a = s; a < e; a++) zs += ld_in(Z, (size_t)a * 3 + c, isf);
        Zb[(size_t)b * 3 + c] = zs * inv;
    }
}

// ---- W2T[l][c][a] = (W_rbf @ We[l])^T ----
__global__ void w2t_k(const void* __restrict__ W_rbf, const void* __restrict__ We,
                      const int* __restrict__ flag, u16* __restrict__ W2T) {
    int isf = flag[0];
    int l = blockIdx.y;
    int gid = blockIdx.x * 256 + threadIdx.x;
    int c = gid >> 6, a = gid & 63;
    float s = 0.f;
    for (int j = 0; j < EDG; j++)
        s += ld_in(W_rbf, a * EDG + j, isf) * ld_in(We, (size_t)l * EDG * EDG + j * EDG + c, isf);
    W2T[l * EDG * RAD + c * RAD + a] = f2b(s);
}

// ---- transpose raw [R][C] (element base) -> bf16 [C][R] ----
__global__ void xpose_k(const void* __restrict__ in, size_t elemBase, u16* __restrict__ out,
                        int R, int C, const int* __restrict__ flag) {
    int isf = flag[0];
    int gid = blockIdx.x * 256 + threadIdx.x;
    if (gid >= R * C) return;
    int r = gid / C, c = gid - r * C;
    out[c * R + r] = f2b(ld_in(in, elemBase + gid, isf));
}

// ==== counting sort of edges by dst ====
__global__ void hist_k(const void* __restrict__ edges, const int* __restrict__ iflag,
                       int* __restrict__ cnt) {
    int i64f = iflag[0];
    int e = blockIdx.x * 256 + threadIdx.x;
    if (e >= NED) return;
    atomicAdd(&cnt[ld_idx(edges, (size_t)NED + e, i64f)], 1);
}

__global__ void scanA_k(const int* __restrict__ cnt, int* __restrict__ dstart,
                        int* __restrict__ bsum) {
    __shared__ int s[256];
    int tid = threadIdx.x;
    int i = blockIdx.x * 256 + tid;
    int x = (i < NBL) ? cnt[i] : 0;
    s[tid] = x;
    __syncthreads();
    for (int off = 1; off < 256; off <<= 1) {
        int t = (tid >= off) ? s[tid - off] : 0;
        __syncthreads();
        s[tid] += t;
        __syncthreads();
    }
    if (i < NBL) dstart[i] = s[tid] - x;      // exclusive within block
    if (tid == 255) bsum[blockIdx.x] = s[255];
}

__global__ void scanB_k(const int* __restrict__ bsum, int* __restrict__ bsumx, int nb) {
    __shared__ int s[256];
    int tid = threadIdx.x;
    int x = (tid < nb) ? bsum[tid] : 0;
    s[tid] = x;
    __syncthreads();
    for (int off = 1; off < 256; off <<= 1) {
        int t = (tid >= off) ? s[tid - off] : 0;
        __syncthreads();
        s[tid] += t;
        __syncthreads();
    }
    if (tid < nb) bsumx[tid] = s[tid] - x;
}

__global__ void scanC_k(int* __restrict__ dstart, const int* __restrict__ bsumx,
                        int* __restrict__ ofs) {
    int i = blockIdx.x * 256 + threadIdx.x;
    if (i < NBL) {
        int v = dstart[i] + bsumx[i >> 8];
        dstart[i] = v;
        ofs[i] = v;
    }
    if (i == NBL) dstart[NBL] = NED;
}

// scatter edges into dst-sorted arrays; fuse distance computation
__global__ void scatter_k(const void* __restrict__ edges, const int* __restrict__ iflag,
                          const float* __restrict__ Zb, int* __restrict__ ofs,
                          int* __restrict__ eSrc, float* __restrict__ eDist) {
    int i64f = iflag[0];
    int e = blockIdx.x * 256 + threadIdx.x;
    if (e >= NED) return;
    int s = ld_idx(edges, e, i64f);
    int d = ld_idx(edges, (size_t)NED + e, i64f);
    float dx = Zb[s * 3 + 0] - Zb[d * 3 + 0];
    float dy = Zb[s * 3 + 1] - Zb[d * 3 + 1];
    float dz = Zb[s * 3 + 2] - Zb[d * 3 + 2];
    float dd = sqrtf(dx * dx + dy * dy + dz * dz + 1e-12f);
    int pos = atomicAdd(&ofs[d], 1);
    eSrc[pos] = s;
    eDist[pos] = dd;
}

// ---- EW table: tbl[i][c] = sum_a exp(-10*(d_i - c_a)^2) * W2[a][c], f32 ----
__global__ void tbl_k(const u16* __restrict__ W2c, float* __restrict__ tbl, int NCl) {
    int i = blockIdx.x;                 // 0..TSAMP (inclusive -> 1025 rows)
    int tid = threadIdx.x;
    __shared__ float g[64];
    float d = (float)i * (8.0f / (float)TSAMP);
    if (tid < 64) {
        float u = d - (float)tid * (6.0f / 63.0f);
        g[tid] = __expf(-10.0f * u * u);
    }
    __syncthreads();
    for (int c = tid; c < NCl; c += 256) {
        const u16* wp = W2c + (size_t)c * RAD;
        float s = 0.f;
#pragma unroll
        for (int a = 0; a < 64; a++) s += g[a] * b2f(wp[a]);
        tbl[(size_t)i * NCl + c] = s;
    }
}

// ---- message+aggregate: one block per dst, no atomics ----
template<int V>
__global__ __launch_bounds__(256) void msg_k(
    const u16* __restrict__ P12, const int* __restrict__ dstart,
    const int* __restrict__ eSrc, const float* __restrict__ eDist,
    const float* __restrict__ tbl, float* __restrict__ agg)
{
    const int NCl = 64 * V;
    int b = blockIdx.x;
    int tid = threadIdx.x, w = tid >> 6, lane = tid & 63;
    int s0 = dstart[b], s1 = dstart[b + 1];
    float p2[V], acc[V];
    {
        u16 tmp[V];
        __builtin_memcpy(tmp, P12 + (size_t)b * (2 * NCl) + NCl + lane * V, V * 2);
#pragma unroll
        for (int j = 0; j < V; j++) { p2[j] = b2f(tmp[j]); acc[j] = 0.f; }
    }
    for (int e = s0 + w; e < s1; e += 4) {
        int src = eSrc[e];
        float d = eDist[e];
        float t = fminf(d, 7.9921875f) * ((float)TSAMP / 8.0f);
        int i0 = (int)t;
        float fr = t - (float)i0;
        float t0[V], t1[V]; u16 p1[V];
        __builtin_memcpy(t0, tbl + (size_t)i0 * NCl + lane * V, V * 4);
        __builtin_memcpy(t1, tbl + (size_t)(i0 + 1) * NCl + lane * V, V * 4);
        __builtin_memcpy(p1, P12 + (size_t)src * (2 * NCl) + lane * V, V * 2);
#pragma unroll
        for (int j = 0; j < V; j++) {
            float ew = t0[j] + fr * (t1[j] - t0[j]);
            float vv = b2f(p1[j]) + p2[j] + ew;
            acc[j] += silu_f(vv);
        }
    }
    __shared__ float red[4 * 256];
#pragma unroll
    for (int j = 0; j < V; j++) red[w * NCl + lane * V + j] = acc[j];
    __syncthreads();
    for (int c = tid; c < NCl; c += 256) {
        float s = red[c] + red[NCl + c] + red[2 * NCl + c] + red[3 * NCl + c];
        agg[(size_t)b * NCl + c] = s;
    }
}

// ---- generic MFMA GEMM, tile 64(M) x (16*NFRAG)(N), K-chunks of 64 ----
enum { EP_B16 = 0, EP_F32 = 1, EP_UPD = 2, EP_ACC = 3 };

template<int MODE, int K, int NFRAG>
__global__ __launch_bounds__(256) void gemm_k(
    const u16* __restrict__ A, const float* __restrict__ Af, int M, int ldA,
    const u16* __restrict__ BT, int ldB,
    u16* __restrict__ outB, float* __restrict__ outF, int ldOut)
{
    __shared__ __attribute__((aligned(16))) u16 sA[64 * 72];
    __shared__ __attribute__((aligned(16))) u16 sB[128 * 72];
    const int tid = threadIdx.x;
    const int w = tid >> 6, lane = tid & 63, quad = lane >> 4, m16 = lane & 15;
    const int rowBase = blockIdx.x * 64;
    const int nt = blockIdx.y;
    f32x4 acc[NFRAG];
#pragma unroll
    for (int f = 0; f < NFRAG; f++) acc[f] = (f32x4){0.f, 0.f, 0.f, 0.f};

    for (int kc = 0; kc < K; kc += 64) {
        if (MODE == EP_UPD || MODE == EP_ACC) {
#pragma unroll
            for (int p = tid; p < 512; p += 256) {
                int row = p >> 3, sub = p & 7;
                int gr = min(rowBase + row, M - 1);
                const float* sp = Af + (size_t)gr * ldA + kc + sub * 8;
                float4 v0 = *(const float4*)(const void*)sp;
                float4 v1 = *(const float4*)(const void*)(sp + 4);
                uint4 pk;
                pk.x = (u32)f2b(v0.x) | ((u32)f2b(v0.y) << 16);
                pk.y = (u32)f2b(v0.z) | ((u32)f2b(v0.w) << 16);
                pk.z = (u32)f2b(v1.x) | ((u32)f2b(v1.y) << 16);
                pk.w = (u32)f2b(v1.z) | ((u32)f2b(v1.w) << 16);
                *(uint4*)(void*)(&sA[row * 72 + sub * 8]) = pk;
            }
        } else {
#pragma unroll
            for (int p = tid; p < 512; p += 256) {
                int row = p >> 3, sub = p & 7;
                int gr = min(rowBase + row, M - 1);
                uint4 v = *(const uint4*)(const void*)(A + (size_t)gr * ldA + kc + sub * 8);
                *(uint4*)(void*)(&sA[row * 72 + sub * 8]) = v;
            }
        }
#pragma unroll
        for (int p = tid; p < NFRAG * 128; p += 256) {
            int row = p >> 3, sub = p & 7;
            uint4 v = *(const uint4*)(const void*)(BT + (size_t)(nt * 16 * NFRAG + row) * ldB + kc + sub * 8);
            *(uint4*)(void*)(&sB[row * 72 + sub * 8]) = v;
        }
        __syncthreads();
#pragma unroll
        for (int ks = 0; ks < 2; ks++) {
            bf16x8 af = *(const bf16x8*)(const void*)(&sA[(w * 16 + m16) * 72 + ks * 32 + quad * 8]);
#pragma unroll
            for (int f = 0; f < NFRAG; f++) {
                bf16x8 bfr = *(const bf16x8*)(const void*)(&sB[(f * 16 + m16) * 72 + ks * 32 + quad * 8]);
                acc[f] = __builtin_amdgcn_mfma_f32_16x16x32_bf16(af, bfr, acc[f], 0, 0, 0);
            }
        }
        __syncthreads();
    }

    // C/D layout: col = 16*f + (lane&15), row = 16*w + quad*4 + reg
#pragma unroll
    for (int f = 0; f < NFRAG; f++) {
        int col = nt * 16 * NFRAG + f * 16 + m16;
#pragma unroll
        for (int rg = 0; rg < 4; rg++) {
            int rl = w * 16 + quad * 4 + rg;
            int r = rowBase + rl;
            if (r < M) {
                float v = acc[f][rg];
                if (MODE == EP_B16) {
                    outB[(size_t)r * ldOut + col] = f2b(v);
                } else if (MODE == EP_F32) {
                    outF[(size_t)r * ldOut + col] = v;
                } else if (MODE == EP_UPD) {
                    size_t ix = (size_t)r * HID + col;
                    outB[ix] = f2b(b2f(outB[ix]) + silu_f(v));
                } else { // EP_ACC
                    outF[(size_t)r * HID + col] += v;
                }
            }
        }
    }
}

// ---- finalize layer (S>1 path): hbf += silu(hacc) ----
__global__ void finalize_k(const float* __restrict__ hacc, u16* __restrict__ hbf) {
    int gid = blockIdx.x * 256 + threadIdx.x;
    float nh = b2f(hbf[gid]) + silu_f(hacc[gid]);
    hbf[gid] = f2b(nh);
}

// ---- block_repr row l2norm -> out1 (f32) ----
__global__ void normb_k(const float* __restrict__ brepr, float* __restrict__ out1) {
    int t = blockIdx.x * 256 + threadIdx.x;
    int b = t >> 6, lane = t & 63;
    float2 x = *(const float2*)(const void*)&brepr[(size_t)b * HID + lane * 2];
    float ss = x.x * x.x + x.y * x.y;
#pragma unroll
    for (int off = 32; off; off >>= 1) ss += __shfl_xor(ss, off);
    float inv = 1.0f / fmaxf(sqrtf(ss), 1e-12f);
    float2 o = make_float2(x.x * inv, x.y * inv);
    *(float2*)(void*)&out1[(size_t)b * HID + lane * 2] = o;
}

// ---- graph readout ----
__global__ void gsum_k(const float* __restrict__ out1, const int* __restrict__ gstart,
                       float* __restrict__ out2) {
    int g = blockIdx.x, c = threadIdx.x;
    int s = gstart[g], e = gstart[g + 1];
    float sum = 0.f;
    for (int r = s; r < e; r++) sum += out1[(size_t)r * HID + c];
    __shared__ float red[HID];
    red[c] = sum * sum;
    __syncthreads();
    for (int o = 64; o; o >>= 1) { if (c < o) red[c] += red[c + o]; __syncthreads(); }
    float inv = 1.0f / fmaxf(sqrtf(red[0]), 1e-12f);
    out2[(size_t)g * HID + c] = sum * inv;
}

extern "C" void kernel_launch(void* const* d_in, const int* in_sizes, int n_in,
                              void* d_out, int out_size, void* d_ws, size_t ws_size,
                              hipStream_t stream) {
    int iH = 0, iZ = 1, iWrbf = 2, iWm1 = 3, iWm2 = 4, iWe = 5, iWupd = 6, iWout = 7,
        iBid = 8, iGid = 9, iEdg = 10;
    {
        int h = -1, z = -1, we = -1, ed = -1, bi = -1, gi = -1;
        int s16[2] = {-1, -1}; int n16 = 0;
        int s98[3] = {-1, -1, -1}; int n98 = 0;
        for (int i = 0; i < n_in; i++) {
            int s = in_sizes[i];
            if (s == 25600000) h = i;
            else if (s == 600000) z = i;
            else if (s == 196608) we = i;
            else if (s == 900000) ed = i;
            else if (s == 200000) bi = i;
            else if (s == 50000) gi = i;
            else if (s == 16384 && n16 < 2) s16[n16++] = i;
            else if (s == 98304 && n98 < 3) s98[n98++] = i;
        }
        if (h >= 0 && z >= 0 && we >= 0 && ed >= 0 && bi >= 0 && gi >= 0 && n16 == 2 && n98 == 3) {
            iH = h; iZ = z; iWe = we; iEdg = ed; iBid = bi; iGid = gi;
            iWm1 = s98[0]; iWm2 = s98[1]; iWupd = s98[2];
            bool alpha = (s16[0] == 1 && s16[1] == 2);
            iWout = alpha ? s16[0] : s16[1];
            iWrbf = alpha ? s16[1] : s16[0];
        }
    }
    const void* H     = d_in[iH];
    const void* Z     = d_in[iZ];
    const void* W_rbf = d_in[iWrbf];
    const void* Wm1   = d_in[iWm1];
    const void* Wm2   = d_in[iWm2];
    const void* We    = d_in[iWe];
    const void* Wupd  = d_in[iWupd];
    const void* W_out = d_in[iWout];
    const void* block_id = d_in[iBid];
    const void* batch_id = d_in[iGid];
    const void* edges    = d_in[iEdg];

    const size_t MB = 1024 * 1024;
    // R6 evidence: S=1 path ran (FETCH ~207MB/dispatch matches full-col EP_MSG) => ws >= 146MB.
    int S = (ws_size >= 132 * MB) ? 1 : (ws_size >= 95 * MB) ? 2 : 4;
    const int NC = 256 / S;
    const int V  = NC / 64;   // 4 / 2 / 1

    char* ws = (char*)d_ws;
    size_t off = 0;
    auto alloc = [&](size_t bytes) -> void* {
        void* p = ws + off;
        off += (bytes + 255) & ~(size_t)255;
        return p;
    };
    int*   flag   = (int*)alloc(256);
    int*   iflag  = (int*)alloc(256);
    int*   start  = (int*)alloc((NBL + 1) * sizeof(int));
    int*   gstart = (int*)alloc((NGR + 1) * sizeof(int));
    int*   cnt    = (int*)alloc((size_t)NBL * 4);
    int*   dstart = (int*)alloc((size_t)(NBL + 1) * 4);
    int*   ofs    = (int*)alloc((size_t)NBL * 4);
    int*   bsum   = (int*)alloc(256 * 4);
    int*   bsumx  = (int*)alloc(256 * 4);
    u16*   hbf    = (u16*)alloc((size_t)NBL * HID * 2);
    float* Zb     = (float*)alloc((size_t)NBL * 3 * 4);
    int*   eSrc   = (int*)alloc((size_t)NED * 4);
    float* eDist  = (float*)alloc((size_t)NED * 4);
    u16*   W2T    = (u16*)alloc((size_t)NLY * EDG * RAD * 2);
    u16*   W12T   = (u16*)alloc((size_t)NLY * 2 * EDG * HID * 2);  // [l][512][128]
    u16*   WupdT  = (u16*)alloc((size_t)NLY * HID * EDG * 2);
    u16*   WoutT  = (u16*)alloc((size_t)HID * HID * 2);
    float* tbl    = (float*)alloc((size_t)(TSAMP + 1) * NC * 4);
    u16*   P12    = (u16*)alloc((size_t)NBL * 2 * NC * 2);
    float* agg    = (float*)alloc((size_t)NBL * NC * 4);
    float* hacc   = (S > 1) ? (float*)alloc((size_t)NBL * HID * 4) : nullptr;
    float* brepr  = agg;   // overlay: agg dead after last update GEMM

    float* out0 = (float*)d_out;
    float* out1 = out0 + (size_t)NBL * HID;
    float* out2 = out1 + (size_t)NBL * HID;

    const int TNB = (NBL + 63) / 64;           // 782
    const int NB2 = (NBL + 256) / 256;         // 196 (covers NBL+1 ids)

    detect_k<<<1, 256, 0, stream>>>(H, flag);
    detecti_k<<<1, 256, 0, stream>>>(block_id, iflag);
    find_starts_k<<<NB2, 256, 0, stream>>>(block_id, NAT, NBL, iflag, start);
    find_starts_k<<<1, 256, 0, stream>>>(batch_id, NBL, NGR, iflag, gstart);
    pool_k<<<NBL, HID, 0, stream>>>(H, Z, start, flag, out0, hbf, Zb);
    w2t_k<<<dim3(64, NLY), 256, 0, stream>>>(W_rbf, We, flag, W2T);
    for (int l = 0; l < NLY; l++) {
        // W12T[l]: rows 0..255 = Wm1[l]^T, rows 256..511 = Wm2[l]^T  (each [EDG][HID])
        xpose_k<<<128, 256, 0, stream>>>(Wm1, (size_t)l * HID * EDG,
                                         W12T + (size_t)l * 2 * EDG * HID, HID, EDG, flag);
        xpose_k<<<128, 256, 0, stream>>>(Wm2, (size_t)l * HID * EDG,
                                         W12T + (size_t)l * 2 * EDG * HID + (size_t)EDG * HID, HID, EDG, flag);
        xpose_k<<<128, 256, 0, stream>>>(Wupd, (size_t)l * EDG * HID,
                                         WupdT + (size_t)l * HID * EDG, EDG, HID, flag);
    }
    xpose_k<<<64, 256, 0, stream>>>(W_out, 0, WoutT, HID, HID, flag);

    // ---- counting sort of edges by dst ----
    hipMemsetAsync(cnt, 0, (size_t)NBL * 4, stream);
    hist_k<<<(NED + 255) / 256, 256, 0, stream>>>(edges, iflag, cnt);
    scanA_k<<<NB2, 256, 0, stream>>>(cnt, dstart, bsum);
    scanB_k<<<1, 256, 0, stream>>>(bsum, bsumx, NB2);
    scanC_k<<<NB2, 256, 0, stream>>>(dstart, bsumx, ofs);
    scatter_k<<<(NED + 255) / 256, 256, 0, stream>>>(edges, iflag, Zb, ofs, eSrc, eDist);

    for (int l = 0; l < NLY; l++) {
        if (S > 1) hipMemsetAsync(hacc, 0, (size_t)NBL * HID * 4, stream);
        for (int c = 0; c < S; c++) {
            const int c0 = c * NC;
            const u16* w12l = W12T + (size_t)l * 2 * EDG * HID;
            if (S == 1) {
                // P12 = hbf @ [Wm1|Wm2], 512 cols in one dispatch
                gemm_k<EP_B16, 128, 8><<<dim3(TNB, 4), 256, 0, stream>>>(
                    hbf, nullptr, NBL, HID, w12l, HID, P12, nullptr, 512);
            } else {
                // chunked: P1 cols c0..c0+NC-1 -> P12[.., 0..NC), P2 chunk -> P12[.., NC..2NC)
                if (V == 2) {
                    gemm_k<EP_B16, 128, 8><<<dim3(TNB, 1), 256, 0, stream>>>(
                        hbf, nullptr, NBL, HID, w12l + (size_t)c0 * HID, HID, P12, nullptr, 2 * NC);
                    gemm_k<EP_B16, 128, 8><<<dim3(TNB, 1), 256, 0, stream>>>(
                        hbf, nullptr, NBL, HID, w12l + (size_t)(EDG + c0) * HID, HID, P12 + NC, nullptr, 2 * NC);
                } else {
                    gemm_k<EP_B16, 128, 4><<<dim3(TNB, 1), 256, 0, stream>>>(
                        hbf, nullptr, NBL, HID, w12l + (size_t)c0 * HID, HID, P12, nullptr, 2 * NC);
                    gemm_k<EP_B16, 128, 4><<<dim3(TNB, 1), 256, 0, stream>>>(
                        hbf, nullptr, NBL, HID, w12l + (size_t)(EDG + c0) * HID, HID, P12 + NC, nullptr, 2 * NC);
                }
            }
            // EW table for this layer/chunk
            tbl_k<<<TSAMP + 1, 256, 0, stream>>>(W2T + (size_t)l * EDG * RAD + (size_t)c0 * RAD, tbl, NC);
            // message + aggregate (no atomics)
            if (V == 4)      msg_k<4><<<NBL, 256, 0, stream>>>(P12, dstart, eSrc, eDist, tbl, agg);
            else if (V == 2) msg_k<2><<<NBL, 256, 0, stream>>>(P12, dstart, eSrc, eDist, tbl, agg);
            else             msg_k<1><<<NBL, 256, 0, stream>>>(P12, dstart, eSrc, eDist, tbl, agg);
            // update
            if (S == 1) {
                gemm_k<EP_UPD, 256, 8><<<dim3(TNB, 1), 256, 0, stream>>>(
                    nullptr, agg, NBL, NC, WupdT + (size_t)l * HID * EDG, EDG, hbf, nullptr, HID);
            } else if (S == 2) {
                gemm_k<EP_ACC, 128, 8><<<dim3(TNB, 1), 256, 0, stream>>>(
                    nullptr, agg, NBL, NC, WupdT + (size_t)l * HID * EDG + c0, EDG, nullptr, hacc, HID);
            } else {
                gemm_k<EP_ACC, 64, 8><<<dim3(TNB, 1), 256, 0, stream>>>(
                    nullptr, agg, NBL, NC, WupdT + (size_t)l * HID * EDG + c0, EDG, nullptr, hacc, HID);
            }
        }
        if (S > 1) finalize_k<<<(size_t)NBL * HID / 256, 256, 0, stream>>>(hacc, hbf);
    }

    // block_repr = h @ W_out -> f32, then row-l2norm -> out1, graph readout -> out2
    gemm_k<EP_F32, 128, 8><<<dim3(TNB, 1), 256, 0, stream>>>(
        hbf, nullptr, NBL, HID, WoutT, HID, nullptr, brepr, HID);
    normb_k<<<(size_t)NBL * 64 / 256, 256, 0, stream>>>(brepr, out1);
    gsum_k<<<NGR, HID, 0, stream>>>(out1, gstart, out2);
}